// Round 1
// baseline (2524.740 us; speedup 1.0000x reference)
//
#include <hip/hip_runtime.h>

// EquiConv fused pipeline, fp32 baseline.
// E = 200000, MUL_S = 128, MUL_V = 64, FC_IN = 128, FC_HID = 64, LEN_W = 192.
//
// ws layout (floats):
//   [0)        Wbig  128x256  = [w1_p0|w1_p1|w1_p2] cols pre-scaled by w2_*, INV_S, SQ2
//   [32768)    Wd    64x192   = [w1_p4|w1_p5] cols pre-scaled by w2_*, INV_V, SQ3, SQ2
//   [45056)    Wp3   64x64    = w1_p3 cols pre-scaled by w2_p3, INV_V, SQ2
//   [49152)    wfc   E x 192  FC path output
// d_out doubles as S1 scratch: s1_kernel writes raw a012 accumulators to cols 0..255
// of each 320-col output row; main_kernel consumes them and overwrites all 320 cols.

#define FMA4(P, X, W) { (P)[0] += (X)*(W).x; (P)[1] += (X)*(W).y; \
                        (P)[2] += (X)*(W).z; (P)[3] += (X)*(W).w; }

__device__ __forceinline__ float sigmoidf_(float x) { return 1.0f / (1.0f + __expf(-x)); }

// ---------------------------------------------------------------- prep
__global__ __launch_bounds__(256) void prep_weights(
    const float* __restrict__ w1_p0, const float* __restrict__ w2_p0,
    const float* __restrict__ w1_p1, const float* __restrict__ w2_p1,
    const float* __restrict__ w1_p2, const float* __restrict__ w2_p2,
    const float* __restrict__ w1_p3, const float* __restrict__ w2_p3,
    const float* __restrict__ w1_p4, const float* __restrict__ w2_p4,
    const float* __restrict__ w1_p5, const float* __restrict__ w2_p5,
    float* __restrict__ Wbig, float* __restrict__ Wd, float* __restrict__ Wp3)
{
    const float INV_S = 0.08838834764831845f;   // 1/sqrt(128)
    const float INV_V = 0.125f;                 // 1/sqrt(64)
    const float SQ2   = 0.7071067811865476f;
    const float SQ3   = 0.5773502691896258f;
    int gid = blockIdx.x * 256 + threadIdx.x;
    if (gid < 128*256) {
        int k = gid >> 8, c = gid & 255;
        float v;
        if (c < 128)      v = w1_p0[k*128 + c]       * w2_p0[c]       * (INV_S*SQ2);
        else if (c < 192) v = w1_p1[k*64 + (c-128)]  * w2_p1[c-128]   * (INV_S*SQ2);
        else              v = w1_p2[k*64 + (c-192)]  * w2_p2[c-192]   * (INV_S*SQ2);
        Wbig[gid] = v;
    } else if (gid < 128*256 + 64*192) {
        int g = gid - 128*256;
        int u = g / 192, c = g - u*192;
        float v;
        if (c < 128) v = w1_p4[u*128 + c]        * w2_p4[c]     * (INV_V*SQ3*SQ2);
        else         v = w1_p5[u*64 + (c-128)]   * w2_p5[c-128] * (INV_V*SQ3*SQ2);
        Wd[g] = v;
    } else if (gid < 128*256 + 64*192 + 64*64) {
        int g = gid - (128*256 + 64*192);
        int w = g & 63;
        Wp3[g] = w1_p3[g] * w2_p3[w] * (INV_V*SQ2);
    }
}

// ---------------------------------------------------------------- FC path
// block = 256 threads, 64 edges/block. eg = edge (t>>2), cg = col group (t&3).
__global__ __launch_bounds__(256) void fc_kernel(
    const float* __restrict__ fw,
    const float* __restrict__ fc_w0, const float* __restrict__ fc_b0,
    const float* __restrict__ fc_w1, const float* __restrict__ fc_b1,
    const float* __restrict__ fc_w2, const float* __restrict__ fc_b2,
    float* __restrict__ wfc)
{
    __shared__ float lds_fw[64*132];   // fw tile; later aliased as h1 (64*65)
    __shared__ float lds_h0[64*65];
    const int t  = threadIdx.x;
    const long e0 = (long)blockIdx.x * 64;

    #pragma unroll
    for (int r = 0; r < 8; ++r) {
        int f = t + r*256;             // 0..2047 -> 64 rows x 32 float4
        int e = f >> 5, c4 = f & 31;
        float4 v = *(const float4*)(fw + (e0 + e)*128 + c4*4);
        *(float4*)(&lds_fw[e*132 + c4*4]) = v;
    }
    __syncthreads();

    const int eg = t >> 2;             // 0..63
    const int cg = t & 3;              // 0..3, 16 cols each

    // layer 0: K=128
    float acc[16];
    #pragma unroll
    for (int j = 0; j < 16; ++j) acc[j] = 0.f;
    for (int k = 0; k < 128; ++k) {
        float xk = lds_fw[eg*132 + k];
        const float4* wr = (const float4*)(fc_w0 + k*64 + cg*16);
        float4 w0 = wr[0], w1 = wr[1], w2 = wr[2], w3 = wr[3];
        FMA4(acc + 0,  xk, w0); FMA4(acc + 4,  xk, w1);
        FMA4(acc + 8,  xk, w2); FMA4(acc + 12, xk, w3);
    }
    #pragma unroll
    for (int j = 0; j < 16; ++j) {
        float z = acc[j] + fc_b0[cg*16 + j];
        lds_h0[eg*65 + cg*16 + j] = z * sigmoidf_(z);
    }
    __syncthreads();

    // layer 1: K=64
    #pragma unroll
    for (int j = 0; j < 16; ++j) acc[j] = 0.f;
    for (int k = 0; k < 64; ++k) {
        float xk = lds_h0[eg*65 + k];
        const float4* wr = (const float4*)(fc_w1 + k*64 + cg*16);
        float4 w0 = wr[0], w1 = wr[1], w2 = wr[2], w3 = wr[3];
        FMA4(acc + 0,  xk, w0); FMA4(acc + 4,  xk, w1);
        FMA4(acc + 8,  xk, w2); FMA4(acc + 12, xk, w3);
    }
    float* lds_h1 = lds_fw;            // alias: lds_fw fully consumed in layer 0
    #pragma unroll
    for (int j = 0; j < 16; ++j) {
        float z = acc[j] + fc_b1[cg*16 + j];
        lds_h1[eg*65 + cg*16 + j] = z * sigmoidf_(z);
    }
    __syncthreads();

    // layer 2: K=64, N=192 (48 cols/thread)
    float acc2[48];
    #pragma unroll
    for (int j = 0; j < 48; ++j) acc2[j] = 0.f;
    for (int k = 0; k < 64; ++k) {
        float xk = lds_h1[eg*65 + k];
        const float4* wr = (const float4*)(fc_w2 + k*192 + cg*48);
        #pragma unroll
        for (int q = 0; q < 12; ++q) {
            float4 w = wr[q];
            FMA4(acc2 + q*4, xk, w);
        }
    }
    float* dst = wfc + (e0 + eg)*192 + cg*48;
    #pragma unroll
    for (int q = 0; q < 12; ++q) {
        float4 o;
        o.x = acc2[q*4+0] + fc_b2[cg*48 + q*4 + 0];
        o.y = acc2[q*4+1] + fc_b2[cg*48 + q*4 + 1];
        o.z = acc2[q*4+2] + fc_b2[cg*48 + q*4 + 2];
        o.w = acc2[q*4+3] + fc_b2[cg*48 + q*4 + 3];
        *(float4*)(dst + q*4) = o;
    }
}

// ---------------------------------------------------------------- S1 = x1s @ Wbig
// block = 256, 64 edges/block, thread tile 4e x 16c, K=128. Writes d_out cols 0..255.
__global__ __launch_bounds__(256) void s1_kernel(
    const float* __restrict__ fea_in1, const float* __restrict__ Wbig,
    float* __restrict__ out)
{
    __shared__ float lds_x[64*132];
    const int t  = threadIdx.x;
    const long e0 = (long)blockIdx.x * 64;
    #pragma unroll
    for (int r = 0; r < 8; ++r) {
        int f = t + r*256;
        int e = f >> 5, c4 = f & 31;
        *(float4*)(&lds_x[e*132 + c4*4]) =
            *(const float4*)(fea_in1 + (e0 + e)*320 + c4*4);
    }
    __syncthreads();

    const int cg = t & 15;   // 16 cols each
    const int eg = t >> 4;   // 4 edges each
    float a0[16], a1[16], a2[16], a3[16];
    #pragma unroll
    for (int j = 0; j < 16; ++j) { a0[j]=0.f; a1[j]=0.f; a2[j]=0.f; a3[j]=0.f; }

    for (int k = 0; k < 128; ++k) {
        float x0 = lds_x[(eg*4+0)*132 + k];
        float x1 = lds_x[(eg*4+1)*132 + k];
        float x2 = lds_x[(eg*4+2)*132 + k];
        float x3 = lds_x[(eg*4+3)*132 + k];
        const float4* wr = (const float4*)(Wbig + k*256 + cg*16);
        #pragma unroll
        for (int q = 0; q < 4; ++q) {
            float4 w = wr[q];
            FMA4(a0 + q*4, x0, w);
            FMA4(a1 + q*4, x1, w);
            FMA4(a2 + q*4, x2, w);
            FMA4(a3 + q*4, x3, w);
        }
    }
    const float* accs[4] = {a0, a1, a2, a3};
    #pragma unroll
    for (int j = 0; j < 4; ++j) {
        float* dst = out + (e0 + eg*4 + j)*320 + cg*16;
        const float* a = accs[j];
        #pragma unroll
        for (int q = 0; q < 4; ++q) {
            float4 o = {a[q*4+0], a[q*4+1], a[q*4+2], a[q*4+3]};
            *(float4*)(dst + q*4) = o;
        }
    }
}

// ---------------------------------------------------------------- main: d, S2, A3, epilogue
// block = 256, 32 edges/block.
__global__ __launch_bounds__(256) void main_kernel(
    const float* __restrict__ fea_in1, const float* __restrict__ fea_in2,
    const float* __restrict__ Wd, const float* __restrict__ Wp3,
    const float* __restrict__ wfc, float* __restrict__ out)
{
    __shared__ float xvbuf[3*2080];    // xv[i][e][u], stride 65; later aliased by A3 (32*193)
    __shared__ float dbuf[32*65];
    __shared__ float s2buf[32*193];
    __shared__ float x2t[32*4];
    const int t  = threadIdx.x;
    const long e0 = (long)blockIdx.x * 32;

    if (t < 32) {
        float4 v = *(const float4*)(fea_in2 + (e0 + t)*4);
        *(float4*)(&x2t[t*4]) = v;
    }
    #pragma unroll
    for (int r = 0; r < 24; ++r) {
        int f = t + r*256;             // < 6144
        int e = f / 192;
        int rr = f - e*192;
        int u = rr / 3;
        int i = rr - u*3;
        xvbuf[i*2080 + e*65 + u] = fea_in1[(e0 + e)*320 + 128 + rr];
    }
    __syncthreads();

    // d[e][u] = x1v[e][u] . x2v[e]
    {
        const int e = t >> 3, ug = t & 7;
        float c1 = x2t[e*4+1], c2 = x2t[e*4+2], c3 = x2t[e*4+3];
        #pragma unroll
        for (int j = 0; j < 8; ++j) {
            int u = ug*8 + j;
            dbuf[e*65 + u] = xvbuf[0*2080 + e*65 + u]*c1
                           + xvbuf[1*2080 + e*65 + u]*c2
                           + xvbuf[2*2080 + e*65 + u]*c3;
        }
    }
    __syncthreads();

    const int eg = t >> 4;   // 0..15, 2 edges each
    const int cg = t & 15;   // 0..15

    // S2 = d @ Wd (K=64, N=192), thread tile 2e x 12c
    float accS0[12], accS1[12];
    #pragma unroll
    for (int q = 0; q < 12; ++q) { accS0[q]=0.f; accS1[q]=0.f; }
    for (int u = 0; u < 64; ++u) {
        float x0 = dbuf[(eg*2+0)*65 + u];
        float x1 = dbuf[(eg*2+1)*65 + u];
        const float4* wr = (const float4*)(Wd + u*192 + cg*12);
        float4 w0 = wr[0], w1 = wr[1], w2 = wr[2];
        FMA4(accS0 + 0, x0, w0); FMA4(accS0 + 4, x0, w1); FMA4(accS0 + 8, x0, w2);
        FMA4(accS1 + 0, x1, w0); FMA4(accS1 + 4, x1, w1); FMA4(accS1 + 8, x1, w2);
    }

    // A3[e][w][i] = sum_u xv[i][e][u] * Wp3[u][w], thread tile 2e x 4w x 3i
    float accA[2][3][4];
    #pragma unroll
    for (int j = 0; j < 2; ++j)
        #pragma unroll
        for (int i = 0; i < 3; ++i)
            #pragma unroll
            for (int q = 0; q < 4; ++q) accA[j][i][q] = 0.f;
    for (int u = 0; u < 64; ++u) {
        float4 wv = *(const float4*)(Wp3 + u*64 + cg*4);
        #pragma unroll
        for (int j = 0; j < 2; ++j) {
            #pragma unroll
            for (int i = 0; i < 3; ++i) {
                float xq = xvbuf[i*2080 + (eg*2+j)*65 + u];
                FMA4(accA[j][i], xq, wv);
            }
        }
    }
    __syncthreads();   // all xv/d reads complete before aliasing writes

    float* a3l = xvbuf;   // 32*193 = 6176 <= 6240
    #pragma unroll
    for (int j = 0; j < 2; ++j) {
        int e = eg*2 + j;
        const float* aS = (j == 0) ? accS0 : accS1;
        #pragma unroll
        for (int q = 0; q < 12; ++q) s2buf[e*193 + cg*12 + q] = aS[q];
        #pragma unroll
        for (int q = 0; q < 4; ++q)
            #pragma unroll
            for (int i = 0; i < 3; ++i)
                a3l[e*193 + (cg*4 + q)*3 + i] = accA[j][i][q];
    }
    __syncthreads();

    // epilogue: compute all outputs into registers (reads S1 from d_out), then store
    float vals[40];
    #pragma unroll
    for (int r = 0; r < 40; ++r) {
        int f = t + r*256;             // < 10240 = 32*320
        int e = f / 320;
        int c = f - e*320;
        long grow = e0 + e;
        float x2s = x2t[e*4];
        float v;
        if (c < 128) {
            float s1   = out[grow*320 + c];
            float scal = s1*x2s + s2buf[e*193 + c];
            v = scal * sigmoidf_(scal) * wfc[grow*192 + c];
        } else {
            int cc = c - 128;
            int w  = cc / 3;
            int i  = cc - w*3;
            float g     = out[grow*320 + 128 + w]*x2s + s2buf[e*193 + 128 + w];
            float vcoef = out[grow*320 + 192 + w];
            float vec   = vcoef * x2t[e*4 + 1 + i] + a3l[e*193 + cc]*x2s;
            v = sigmoidf_(g) * vec * wfc[grow*192 + 128 + w];
        }
        vals[r] = v;
    }
    __syncthreads();   // all S1 reads drained before any final store
    #pragma unroll
    for (int r = 0; r < 40; ++r) {
        int f = t + r*256;
        out[e0*320 + f] = vals[r];
    }
}

// ---------------------------------------------------------------- launch
extern "C" void kernel_launch(void* const* d_in, const int* in_sizes, int n_in,
                              void* d_out, int out_size, void* d_ws, size_t ws_size,
                              hipStream_t stream) {
    const float* fea_in1 = (const float*)d_in[0];
    const float* fea_in2 = (const float*)d_in[1];
    const float* fea_w   = (const float*)d_in[2];
    // d_in[3] = batch_edge (unused by reference)
    const float* w1_p0 = (const float*)d_in[4];
    const float* w2_p0 = (const float*)d_in[5];
    const float* w1_p1 = (const float*)d_in[6];
    const float* w2_p1 = (const float*)d_in[7];
    const float* w1_p2 = (const float*)d_in[8];
    const float* w2_p2 = (const float*)d_in[9];
    const float* w1_p3 = (const float*)d_in[10];
    const float* w2_p3 = (const float*)d_in[11];
    const float* w1_p4 = (const float*)d_in[12];
    const float* w2_p4 = (const float*)d_in[13];
    const float* w1_p5 = (const float*)d_in[14];
    const float* w2_p5 = (const float*)d_in[15];
    const float* fc_w0 = (const float*)d_in[16];
    const float* fc_b0 = (const float*)d_in[17];
    const float* fc_w1 = (const float*)d_in[18];
    const float* fc_b1 = (const float*)d_in[19];
    const float* fc_w2 = (const float*)d_in[20];
    const float* fc_b2 = (const float*)d_in[21];

    const int E = in_sizes[0] / 320;   // 200000

    float* ws   = (float*)d_ws;
    float* Wbig = ws;                  // 32768
    float* Wd   = ws + 32768;          // 12288
    float* Wp3  = ws + 45056;          // 4096
    float* wfc  = ws + 49152;          // E*192
    float* out  = (float*)d_out;

    prep_weights<<<192, 256, 0, stream>>>(w1_p0, w2_p0, w1_p1, w2_p1, w1_p2, w2_p2,
                                          w1_p3, w2_p3, w1_p4, w2_p4, w1_p5, w2_p5,
                                          Wbig, Wd, Wp3);
    fc_kernel<<<E/64, 256, 0, stream>>>(fea_w, fc_w0, fc_b0, fc_w1, fc_b1,
                                        fc_w2, fc_b2, wfc);
    s1_kernel<<<E/64, 256, 0, stream>>>(fea_in1, Wbig, out);
    main_kernel<<<E/32, 256, 0, stream>>>(fea_in1, fea_in2, Wd, Wp3, wfc, out);
}

// Round 2
// 1359.285 us; speedup vs baseline: 1.8574x; 1.8574x over previous
//
#include <hip/hip_runtime.h>

// EquiConv fused pipeline, fp32, LDS-staged weights (round 1).
// E = 200000, MUL_S = 128, MUL_V = 64, FC_IN = 128, FC_HID = 64, LEN_W = 192.
//
// ws layout (floats):
//   [0)        Wbig  128x256  = [w1_p0|w1_p1|w1_p2] cols pre-scaled by w2_*, INV_S, SQ2
//   [32768)    Wd    64x192   = [w1_p4|w1_p5] cols pre-scaled by w2_*, INV_V, SQ3, SQ2
//   [45056)    Wp3   64x64    = w1_p3 cols pre-scaled by w2_p3, INV_V, SQ2
//   [49152)    wfc   E x 192  FC path output
// d_out doubles as S1 scratch: s1_kernel writes raw accumulators to cols 0..255
// of each 320-col output row; main_kernel consumes them and overwrites all 320 cols.

#define FMA4(P, X, W) { (P)[0] += (X)*(W).x; (P)[1] += (X)*(W).y; \
                        (P)[2] += (X)*(W).z; (P)[3] += (X)*(W).w; }

__device__ __forceinline__ float sigmoidf_(float x) { return 1.0f / (1.0f + __expf(-x)); }

// ---------------------------------------------------------------- prep
__global__ __launch_bounds__(256) void prep_weights(
    const float* __restrict__ w1_p0, const float* __restrict__ w2_p0,
    const float* __restrict__ w1_p1, const float* __restrict__ w2_p1,
    const float* __restrict__ w1_p2, const float* __restrict__ w2_p2,
    const float* __restrict__ w1_p3, const float* __restrict__ w2_p3,
    const float* __restrict__ w1_p4, const float* __restrict__ w2_p4,
    const float* __restrict__ w1_p5, const float* __restrict__ w2_p5,
    float* __restrict__ Wbig, float* __restrict__ Wd, float* __restrict__ Wp3)
{
    const float INV_S = 0.08838834764831845f;   // 1/sqrt(128)
    const float INV_V = 0.125f;                 // 1/sqrt(64)
    const float SQ2   = 0.7071067811865476f;
    const float SQ3   = 0.5773502691896258f;
    int gid = blockIdx.x * 256 + threadIdx.x;
    if (gid < 128*256) {
        int k = gid >> 8, c = gid & 255;
        float v;
        if (c < 128)      v = w1_p0[k*128 + c]       * w2_p0[c]       * (INV_S*SQ2);
        else if (c < 192) v = w1_p1[k*64 + (c-128)]  * w2_p1[c-128]   * (INV_S*SQ2);
        else              v = w1_p2[k*64 + (c-192)]  * w2_p2[c-192]   * (INV_S*SQ2);
        Wbig[gid] = v;
    } else if (gid < 128*256 + 64*192) {
        int g = gid - 128*256;
        int u = g / 192, c = g - u*192;
        float v;
        if (c < 128) v = w1_p4[u*128 + c]        * w2_p4[c]     * (INV_V*SQ3*SQ2);
        else         v = w1_p5[u*64 + (c-128)]   * w2_p5[c-128] * (INV_V*SQ3*SQ2);
        Wd[g] = v;
    } else if (gid < 128*256 + 64*192 + 64*64) {
        int g = gid - (128*256 + 64*192);
        int w = g & 63;
        Wp3[g] = w1_p3[g] * w2_p3[w] * (INV_V*SQ2);
    }
}

// ---------------------------------------------------------------- FC path
// block = 256 threads, 64 edges/block. All weights staged through LDS.
// LDS floats: fw [0,8448) stride 132 | h0 [0,4352) stride 68 (alias) |
//             h1 [4352,8704) stride 68 | wbuf [8704,14848) (24 KB)
__global__ __launch_bounds__(256) void fc_kernel(
    const float* __restrict__ fw,
    const float* __restrict__ fc_w0, const float* __restrict__ fc_b0,
    const float* __restrict__ fc_w1, const float* __restrict__ fc_b1,
    const float* __restrict__ fc_w2, const float* __restrict__ fc_b2,
    float* __restrict__ wfc)
{
    __shared__ float lds[14848];
    float* fwt  = lds;           // 64 x stride 132
    float* h0   = lds;           // 64 x stride 68 (alias, after fw dead)
    float* h1   = lds + 4352;    // 64 x stride 68
    float* wbuf = lds + 8704;    // 6144 floats

    const int t  = threadIdx.x;
    const long e0 = (long)blockIdx.x * 64;
    const int eg = t >> 4;       // 16 groups x 4 edges
    const int cg = t & 15;       // 16 col groups

    #pragma unroll
    for (int r = 0; r < 8; ++r) {
        int f = t + r*256;                    // 2048 float4s
        int e = f >> 5, c4 = f & 31;
        *(float4*)(&fwt[e*132 + c4*4]) = *(const float4*)(fw + (e0 + e)*128 + c4*4);
    }

    // ---- layer 0: K=128, N=64, thread tile 4e x 4c, w0 in 2 chunks of 64 rows
    float acc0[4][4];
    #pragma unroll
    for (int e = 0; e < 4; ++e)
        #pragma unroll
        for (int c = 0; c < 4; ++c) acc0[e][c] = 0.f;
    for (int ch = 0; ch < 2; ++ch) {
        __syncthreads();                      // fw loaded / prev chunk reads done
        #pragma unroll
        for (int r = 0; r < 4; ++r) {
            int f = t + r*256;                // 1024 float4s = 64x64
            int row = f >> 4, c4 = f & 15;
            *(float4*)(&wbuf[row*64 + c4*4]) =
                *(const float4*)(fc_w0 + (ch*64 + row)*64 + c4*4);
        }
        __syncthreads();
        for (int kk = 0; kk < 64; kk += 4) {
            float xa[4][4];
            #pragma unroll
            for (int e = 0; e < 4; ++e) {
                float4 v = *(const float4*)(&fwt[(eg*4 + e)*132 + ch*64 + kk]);
                xa[e][0]=v.x; xa[e][1]=v.y; xa[e][2]=v.z; xa[e][3]=v.w;
            }
            #pragma unroll
            for (int j = 0; j < 4; ++j) {
                float4 wv = *(const float4*)(&wbuf[(kk + j)*64 + cg*4]);
                #pragma unroll
                for (int e = 0; e < 4; ++e) FMA4(acc0[e], xa[e][j], wv);
            }
        }
    }
    __syncthreads();                          // all fw/wbuf reads done
    #pragma unroll
    for (int e = 0; e < 4; ++e)
        #pragma unroll
        for (int c = 0; c < 4; ++c) {
            float z = acc0[e][c] + fc_b0[cg*4 + c];
            h0[(eg*4 + e)*68 + cg*4 + c] = z * sigmoidf_(z);
        }
    // stage w1 (64x64) concurrently with h0 writes (disjoint regions)
    #pragma unroll
    for (int r = 0; r < 4; ++r) {
        int f = t + r*256;
        int row = f >> 4, c4 = f & 15;
        *(float4*)(&wbuf[row*64 + c4*4]) = *(const float4*)(fc_w1 + row*64 + c4*4);
    }
    __syncthreads();

    // ---- layer 1: K=64, N=64, thread tile 4e x 4c
    float acc1[4][4];
    #pragma unroll
    for (int e = 0; e < 4; ++e)
        #pragma unroll
        for (int c = 0; c < 4; ++c) acc1[e][c] = 0.f;
    for (int kk = 0; kk < 64; kk += 4) {
        float xa[4][4];
        #pragma unroll
        for (int e = 0; e < 4; ++e) {
            float4 v = *(const float4*)(&h0[(eg*4 + e)*68 + kk]);
            xa[e][0]=v.x; xa[e][1]=v.y; xa[e][2]=v.z; xa[e][3]=v.w;
        }
        #pragma unroll
        for (int j = 0; j < 4; ++j) {
            float4 wv = *(const float4*)(&wbuf[(kk + j)*64 + cg*4]);
            #pragma unroll
            for (int e = 0; e < 4; ++e) FMA4(acc1[e], xa[e][j], wv);
        }
    }
    // h1 region is disjoint from h0 and wbuf; no sync needed before writes
    #pragma unroll
    for (int e = 0; e < 4; ++e)
        #pragma unroll
        for (int c = 0; c < 4; ++c) {
            float z = acc1[e][c] + fc_b1[cg*4 + c];
            h1[(eg*4 + e)*68 + cg*4 + c] = z * sigmoidf_(z);
        }

    // ---- layer 2: K=64, N=192, thread tile 4e x 12c, w2 in 2 chunks of 32 rows
    float acc2[4][12];
    #pragma unroll
    for (int e = 0; e < 4; ++e)
        #pragma unroll
        for (int c = 0; c < 12; ++c) acc2[e][c] = 0.f;
    for (int ch = 0; ch < 2; ++ch) {
        __syncthreads();                      // h1 written / prev wbuf reads done
        #pragma unroll
        for (int r = 0; r < 6; ++r) {
            int f = t + r*256;                // 1536 float4s = 32x192
            int row = f / 48, c4 = f - row*48;
            *(float4*)(&wbuf[row*192 + c4*4]) =
                *(const float4*)(fc_w2 + (ch*32 + row)*192 + c4*4);
        }
        __syncthreads();
        for (int kk = 0; kk < 32; kk += 4) {
            float xa[4][4];
            #pragma unroll
            for (int e = 0; e < 4; ++e) {
                float4 v = *(const float4*)(&h1[(eg*4 + e)*68 + ch*32 + kk]);
                xa[e][0]=v.x; xa[e][1]=v.y; xa[e][2]=v.z; xa[e][3]=v.w;
            }
            #pragma unroll
            for (int j = 0; j < 4; ++j) {
                float4 w0 = *(const float4*)(&wbuf[(kk + j)*192 + cg*12 + 0]);
                float4 w1 = *(const float4*)(&wbuf[(kk + j)*192 + cg*12 + 4]);
                float4 w2 = *(const float4*)(&wbuf[(kk + j)*192 + cg*12 + 8]);
                #pragma unroll
                for (int e = 0; e < 4; ++e) {
                    FMA4(acc2[e] + 0, xa[e][j], w0);
                    FMA4(acc2[e] + 4, xa[e][j], w1);
                    FMA4(acc2[e] + 8, xa[e][j], w2);
                }
            }
        }
    }
    #pragma unroll
    for (int e = 0; e < 4; ++e) {
        float* dst = wfc + (e0 + eg*4 + e)*192 + cg*12;
        #pragma unroll
        for (int q = 0; q < 3; ++q) {
            float4 o;
            o.x = acc2[e][q*4+0] + fc_b2[cg*12 + q*4 + 0];
            o.y = acc2[e][q*4+1] + fc_b2[cg*12 + q*4 + 1];
            o.z = acc2[e][q*4+2] + fc_b2[cg*12 + q*4 + 2];
            o.w = acc2[e][q*4+3] + fc_b2[cg*12 + q*4 + 3];
            *(float4*)(dst + q*4) = o;
        }
    }
}

// ---------------------------------------------------------------- S1 = x1s @ Wbig
// block = 256, 64 edges/block, thread tile 4e x 16c, K=128.
// Wbig staged through LDS in 8 chunks of 16 rows. Writes d_out cols 0..255.
// LDS floats: xt [0,8448) stride 132 | wbuf [8448,12544)
__global__ __launch_bounds__(256) void s1_kernel(
    const float* __restrict__ fea_in1, const float* __restrict__ Wbig,
    float* __restrict__ out)
{
    __shared__ float lds[12544];
    float* xt   = lds;
    float* wbuf = lds + 8448;

    const int t  = threadIdx.x;
    const long e0 = (long)blockIdx.x * 64;
    const int eg = t >> 4;   // 4 edges each
    const int cg = t & 15;   // 16 cols each

    #pragma unroll
    for (int r = 0; r < 8; ++r) {
        int f = t + r*256;
        int e = f >> 5, c4 = f & 31;
        *(float4*)(&xt[e*132 + c4*4]) =
            *(const float4*)(fea_in1 + (e0 + e)*320 + c4*4);
    }

    float acc[4][16];
    #pragma unroll
    for (int e = 0; e < 4; ++e)
        #pragma unroll
        for (int c = 0; c < 16; ++c) acc[e][c] = 0.f;

    for (int ch = 0; ch < 8; ++ch) {
        __syncthreads();                      // xt loaded / prev chunk reads done
        #pragma unroll
        for (int r = 0; r < 4; ++r) {
            int f = t + r*256;                // 1024 float4s = 16x256
            int row = f >> 6, c4 = f & 63;
            *(float4*)(&wbuf[row*256 + c4*4]) =
                *(const float4*)(Wbig + (ch*16 + row)*256 + c4*4);
        }
        __syncthreads();
        for (int kk = 0; kk < 16; kk += 4) {
            float xa[4][4];
            #pragma unroll
            for (int e = 0; e < 4; ++e) {
                float4 v = *(const float4*)(&xt[(eg*4 + e)*132 + ch*16 + kk]);
                xa[e][0]=v.x; xa[e][1]=v.y; xa[e][2]=v.z; xa[e][3]=v.w;
            }
            #pragma unroll
            for (int j = 0; j < 4; ++j) {
                #pragma unroll
                for (int q = 0; q < 4; ++q) {
                    float4 wv = *(const float4*)(&wbuf[(kk + j)*256 + cg*16 + q*4]);
                    #pragma unroll
                    for (int e = 0; e < 4; ++e) FMA4(acc[e] + q*4, xa[e][j], wv);
                }
            }
        }
    }
    #pragma unroll
    for (int e = 0; e < 4; ++e) {
        float* dst = out + (e0 + eg*4 + e)*320 + cg*16;
        #pragma unroll
        for (int q = 0; q < 4; ++q) {
            float4 o = {acc[e][q*4+0], acc[e][q*4+1], acc[e][q*4+2], acc[e][q*4+3]};
            *(float4*)(dst + q*4) = o;
        }
    }
}

// ---------------------------------------------------------------- main: d, S2, A3, epilogue
// block = 256, 32 edges/block. Wp3 staged fully; Wd in 4 chunks of 16 rows.
// LDS floats: xv 3x(32x68) [0,6528) | dbuf [6528,8704) stride 68 |
//             wbuf [8704,12800) | x2t [12800,12928)
// aliases: a3l = [0,6176) stride 193 ; s2buf = [6528,12704) stride 193
__global__ __launch_bounds__(256) void main_kernel(
    const float* __restrict__ fea_in1, const float* __restrict__ fea_in2,
    const float* __restrict__ Wd, const float* __restrict__ Wp3,
    const float* __restrict__ wfc, float* __restrict__ out)
{
    __shared__ float lds[12928];
    float* xv   = lds;            // [i*2176 + e*68 + u]
    float* dbuf = lds + 6528;     // [e*68 + u]
    float* wbuf = lds + 8704;     // 4096 floats
    float* x2t  = lds + 12800;    // [e*4 + j]

    const int t  = threadIdx.x;
    const long e0 = (long)blockIdx.x * 32;
    const int eg = t >> 4;        // 2 edges each
    const int cg = t & 15;

    if (t < 32) {
        float4 v = *(const float4*)(fea_in2 + (e0 + t)*4);
        *(float4*)(&x2t[t*4]) = v;
    }
    #pragma unroll
    for (int r = 0; r < 24; ++r) {
        int f = t + r*256;        // < 6144
        int e = f / 192;
        int rr = f - e*192;
        int u = rr / 3;
        int i = rr - u*3;
        xv[i*2176 + e*68 + u] = fea_in1[(e0 + e)*320 + 128 + rr];
    }
    #pragma unroll
    for (int r = 0; r < 4; ++r) {
        int g = (t + r*256)*4;    // Wp3: 4096 floats
        *(float4*)(&wbuf[g]) = *(const float4*)(Wp3 + g);
    }
    __syncthreads();

    // d[e][u] = x1v[e][u] . x2v[e]
    {
        const int de = t >> 3, ug = t & 7;
        float c1 = x2t[de*4+1], c2 = x2t[de*4+2], c3 = x2t[de*4+3];
        #pragma unroll
        for (int j = 0; j < 8; ++j) {
            int u = ug*8 + j;
            dbuf[de*68 + u] = xv[0*2176 + de*68 + u]*c1
                            + xv[1*2176 + de*68 + u]*c2
                            + xv[2*2176 + de*68 + u]*c3;
        }
    }
    __syncthreads();

    // A3[e][w][i] = sum_u xv[i][e][u] * Wp3[u][w], thread tile 2e x 4w x 3i
    float accA[2][3][4];
    #pragma unroll
    for (int j = 0; j < 2; ++j)
        #pragma unroll
        for (int i = 0; i < 3; ++i)
            #pragma unroll
            for (int q = 0; q < 4; ++q) accA[j][i][q] = 0.f;
    for (int u = 0; u < 64; u += 4) {
        float4 wq[4];
        #pragma unroll
        for (int j = 0; j < 4; ++j)
            wq[j] = *(const float4*)(&wbuf[(u + j)*64 + cg*4]);
        #pragma unroll
        for (int e = 0; e < 2; ++e)
            #pragma unroll
            for (int i = 0; i < 3; ++i) {
                float4 xq = *(const float4*)(&xv[i*2176 + (eg*2 + e)*68 + u]);
                float xa[4] = {xq.x, xq.y, xq.z, xq.w};
                #pragma unroll
                for (int j = 0; j < 4; ++j) FMA4(accA[e][i], xa[j], wq[j]);
            }
    }

    // S2 = d @ Wd (K=64, N=192), thread tile 2e x 12c, Wd in 4 chunks of 16 rows
    float accS[2][12];
    #pragma unroll
    for (int e = 0; e < 2; ++e)
        #pragma unroll
        for (int q = 0; q < 12; ++q) accS[e][q] = 0.f;
    for (int ch = 0; ch < 4; ++ch) {
        __syncthreads();                      // Wp3 / prev chunk reads done
        #pragma unroll
        for (int r = 0; r < 3; ++r) {
            int f = t + r*256;                // 768 float4s = 16x192
            int row = f / 48, c4 = f - row*48;
            *(float4*)(&wbuf[row*192 + c4*4]) =
                *(const float4*)(Wd + (ch*16 + row)*192 + c4*4);
        }
        __syncthreads();
        for (int uu = 0; uu < 16; uu += 4) {
            float da[2][4];
            #pragma unroll
            for (int e = 0; e < 2; ++e) {
                float4 v = *(const float4*)(&dbuf[(eg*2 + e)*68 + ch*16 + uu]);
                da[e][0]=v.x; da[e][1]=v.y; da[e][2]=v.z; da[e][3]=v.w;
            }
            #pragma unroll
            for (int j = 0; j < 4; ++j) {
                float4 w0 = *(const float4*)(&wbuf[(uu + j)*192 + cg*12 + 0]);
                float4 w1 = *(const float4*)(&wbuf[(uu + j)*192 + cg*12 + 4]);
                float4 w2 = *(const float4*)(&wbuf[(uu + j)*192 + cg*12 + 8]);
                #pragma unroll
                for (int e = 0; e < 2; ++e) {
                    FMA4(accS[e] + 0, da[e][j], w0);
                    FMA4(accS[e] + 4, da[e][j], w1);
                    FMA4(accS[e] + 8, da[e][j], w2);
                }
            }
        }
    }
    __syncthreads();   // all xv/dbuf/wbuf reads complete before aliasing writes

    float* a3l = lds;             // 32 x stride 193 (aliases xv)
    float* s2b = lds + 6528;      // 32 x stride 193 (aliases dbuf+wbuf)
    #pragma unroll
    for (int j = 0; j < 2; ++j) {
        int e = eg*2 + j;
        #pragma unroll
        for (int q = 0; q < 12; ++q) s2b[e*193 + cg*12 + q] = accS[j][q];
        #pragma unroll
        for (int q = 0; q < 4; ++q)
            #pragma unroll
            for (int i = 0; i < 3; ++i)
                a3l[e*193 + (cg*4 + q)*3 + i] = accA[j][i][q];
    }
    __syncthreads();

    // epilogue: compute all outputs into registers (reads S1 from d_out), then store
    float vals[40];
    #pragma unroll
    for (int r = 0; r < 40; ++r) {
        int f = t + r*256;             // < 10240 = 32*320
        int e = f / 320;
        int c = f - e*320;
        long grow = e0 + e;
        float x2s = x2t[e*4];
        float v;
        if (c < 128) {
            float s1   = out[grow*320 + c];
            float scal = s1*x2s + s2b[e*193 + c];
            v = scal * sigmoidf_(scal) * wfc[grow*192 + c];
        } else {
            int cc = c - 128;
            int w  = cc / 3;
            int i  = cc - w*3;
            float g     = out[grow*320 + 128 + w]*x2s + s2b[e*193 + 128 + w];
            float vcoef = out[grow*320 + 192 + w];
            float vec   = vcoef * x2t[e*4 + 1 + i] + a3l[e*193 + cc]*x2s;
            v = sigmoidf_(g) * vec * wfc[grow*192 + 128 + w];
        }
        vals[r] = v;
    }
    __syncthreads();   // all S1 reads drained before any final store
    #pragma unroll
    for (int r = 0; r < 40; ++r) {
        int f = t + r*256;
        out[e0*320 + f] = vals[r];
    }
}

// ---------------------------------------------------------------- launch
extern "C" void kernel_launch(void* const* d_in, const int* in_sizes, int n_in,
                              void* d_out, int out_size, void* d_ws, size_t ws_size,
                              hipStream_t stream) {
    const float* fea_in1 = (const float*)d_in[0];
    const float* fea_in2 = (const float*)d_in[1];
    const float* fea_w   = (const float*)d_in[2];
    // d_in[3] = batch_edge (unused by reference)
    const float* w1_p0 = (const float*)d_in[4];
    const float* w2_p0 = (const float*)d_in[5];
    const float* w1_p1 = (const float*)d_in[6];
    const float* w2_p1 = (const float*)d_in[7];
    const float* w1_p2 = (const float*)d_in[8];
    const float* w2_p2 = (const float*)d_in[9];
    const float* w1_p3 = (const float*)d_in[10];
    const float* w2_p3 = (const float*)d_in[11];
    const float* w1_p4 = (const float*)d_in[12];
    const float* w2_p4 = (const float*)d_in[13];
    const float* w1_p5 = (const float*)d_in[14];
    const float* w2_p5 = (const float*)d_in[15];
    const float* fc_w0 = (const float*)d_in[16];
    const float* fc_b0 = (const float*)d_in[17];
    const float* fc_w1 = (const float*)d_in[18];
    const float* fc_b1 = (const float*)d_in[19];
    const float* fc_w2 = (const float*)d_in[20];
    const float* fc_b2 = (const float*)d_in[21];

    const int E = in_sizes[0] / 320;   // 200000

    float* ws   = (float*)d_ws;
    float* Wbig = ws;                  // 32768
    float* Wd   = ws + 32768;          // 12288
    float* Wp3  = ws + 45056;          // 4096
    float* wfc  = ws + 49152;          // E*192
    float* out  = (float*)d_out;

    prep_weights<<<192, 256, 0, stream>>>(w1_p0, w2_p0, w1_p1, w2_p1, w1_p2, w2_p2,
                                          w1_p3, w2_p3, w1_p4, w2_p4, w1_p5, w2_p5,
                                          Wbig, Wd, Wp3);
    fc_kernel<<<E/64, 256, 0, stream>>>(fea_w, fc_w0, fc_b0, fc_w1, fc_b1,
                                        fc_w2, fc_b2, wfc);
    s1_kernel<<<E/64, 256, 0, stream>>>(fea_in1, Wbig, out);
    main_kernel<<<E/32, 256, 0, stream>>>(fea_in1, fea_in2, Wd, Wp3, wfc, out);
}